// Round 2
// baseline (446.602 us; speedup 1.0000x reference)
//
#include <hip/hip_runtime.h>

#define HW   262144      // 512*512
#define CCH  19
#define BB   8
#define NPIX 39845888ull // B*C*HW

typedef float f4 __attribute__((ext_vector_type(4)));

// ---------------- Kernel A: argmax over channels + 8x8 histogram -> patches^T ----------------
// grid: B*64 blocks (one per (b, bh) 8-row strip), 512 threads.
// Output pT layout: [bc][l=16][k=256] floats (row stride 256, no pad).
__global__ __launch_bounds__(512) void argmax_hist_kernel(
    const float* __restrict__ x, float* __restrict__ pT)
{
    int bid = blockIdx.x;          // b*64 + bh
    int b   = bid >> 6;
    int bh  = bid & 63;
    int t   = threadIdx.x;

    __shared__ int counts[CCH * 64];
    for (int i = t; i < CCH * 64; i += 512) counts[i] = 0;
    __syncthreads();

    // strip: rows [bh*8, bh*8+8) x 512 cols, contiguous 4096 floats per channel
    const float* xb = x + (size_t)b * CCH * HW + (size_t)bh * 4096;
    #pragma unroll
    for (int it = 0; it < 2; ++it) {
        int q = it * 512 + t;                       // float4-quad index in strip [0,1024)
        const float4* xq = (const float4*)xb + q;   // channel stride = HW/4 float4s
        float4 best = xq[0];
        int bx = 0, by = 0, bz = 0, bw4 = 0;
        #pragma unroll
        for (int c = 1; c < CCH; ++c) {
            float4 v = xq[c * (HW / 4)];
            if (v.x > best.x) { best.x = v.x; bx  = c; }
            if (v.y > best.y) { best.y = v.y; by  = c; }
            if (v.z > best.z) { best.z = v.z; bz  = c; }
            if (v.w > best.w) { best.w = v.w; bw4 = c; }
        }
        int off = q * 4;                 // pixel offset in strip; 4 pixels share one 8-block
        int blk = (off & 511) >> 3;      // bw in [0,64)
        atomicAdd(&counts[bx  * 64 + blk], 1);
        atomicAdd(&counts[by  * 64 + blk], 1);
        atomicAdd(&counts[bz  * 64 + blk], 1);
        atomicAdd(&counts[bw4 * 64 + blk], 1);
    }
    __syncthreads();

    // write patches^T: l = (bh/16)*4 + bw/16 ; k = (bh%16)*16 + bw%16
    int l_hi = (bh >> 4) * 4;
    int k_hi = (bh & 15) << 4;
    for (int u = t; u < CCH * 64; u += 512) {
        int c  = u >> 6;
        int bw = u & 63;
        int l  = l_hi + (bw >> 4);
        int k  = k_hi | (bw & 15);
        pT[(((size_t)(b * CCH + c)) * 16 + l) * 256 + k] =
            (float)counts[u] * (1.0f / 64.0f);
    }
}

// ---------------- Kernel C: per-(bc, 4-tile-row) bmm + fold + elementwise combine ------------
// grid: 152*8 = 1216 blocks (XCD-swizzled), 256 threads.
// Each block: 64 rows x 512 cols => three 128KB streams (x read, out0/out1 write).
// p staged once in LDS as [l][k/4] f4; dot = 16 broadcast-scalar x f4 FMAs (no h-sums).
__global__ __launch_bounds__(256) void apply_kernel(
    const float* __restrict__ x, const float* __restrict__ att,
    const float* __restrict__ pT, float* __restrict__ out)
{
    // bijective XCD swizzle: nwg = 1216, 8 XCDs, 152 blocks each
    int bid = blockIdx.x;
    int swz = (bid & 7) * 152 + (bid >> 3);
    int bc  = swz >> 3;      // 0..151 ; all 8 blocks of a bc on one XCD
    int mig = swz & 7;       // tile-row group: rows mi = mig*4 .. mig*4+3

    int t = threadIdx.x;

    __shared__ __align__(16) f4 p_lds[16 * 64];   // [l][k/4], 16 KB
    {
        const f4* pb4 = (const f4*)(pT + (size_t)bc * 4096);
        #pragma unroll
        for (int i = 0; i < 4; ++i) p_lds[t + i * 256] = pb4[t + i * 256];
    }
    __syncthreads();

    int j   = t & 63;          // column group: cols [4j,4j+3] and [256+4j, 256+4j+3]
    int rq  = t >> 6;          // wave id -> row quadrant
    int mj0 = j >> 2;          // tile column 0..15
    int cc0 = (j & 3) << 2;    // within-tile col base

    for (int mm = 0; mm < 4; ++mm) {
        int mi = mig * 4 + mm;
        const f4* aAp = (const f4*)(att + ((size_t)bc * 1024 + (size_t)mi * 32 + mj0) * 16);
        const f4* aBp = (const f4*)(att + ((size_t)bc * 1024 + (size_t)mi * 32 + 16 + mj0) * 16);
        f4 aA[4] = { aAp[0], aAp[1], aAp[2], aAp[3] };
        f4 aB[4] = { aBp[0], aBp[1], aBp[2], aBp[3] };

        size_t gb = (size_t)bc * HW + (size_t)mi * 8192;
        const f4* xg  = (const f4*)(x + gb);
        f4* o0g = (f4*)(out + gb);
        f4* o1g = (f4*)(out + NPIX + gb);

        #pragma unroll 2
        for (int it = 0; it < 4; ++it) {
            int r  = it * 4 + rq;              // row within tile, uniform per wave
            int kq = r * 4 + (cc0 >> 2);       // f4 index of this thread's column group
            const f4* pr = &p_lds[kq];

            f4 p0 = pr[0];
            f4 cA = aA[0][0] * p0;
            f4 cB = aB[0][0] * p0;
            #pragma unroll
            for (int l = 1; l < 16; ++l) {
                f4 p = pr[l * 64];
                cA += aA[l >> 2][l & 3] * p;
                cB += aB[l >> 2][l & 3] * p;
            }

            int rowo = r * 128 + j;
            f4 v0 = xg[rowo];
            f4 v1 = xg[rowo + 64];
            f4 y0 = v0 + cA * v0;
            f4 y1 = v1 + cB * v1;
            f4 z0 = y0 + cA * y0;
            f4 z1 = y1 + cB * y1;
            __builtin_nontemporal_store(z0, &o0g[rowo]);
            __builtin_nontemporal_store(z1, &o0g[rowo + 64]);
            __builtin_nontemporal_store(cA, &o1g[rowo]);
            __builtin_nontemporal_store(cB, &o1g[rowo + 64]);
        }
    }
}

extern "C" void kernel_launch(void* const* d_in, const int* in_sizes, int n_in,
                              void* d_out, int out_size, void* d_ws, size_t ws_size,
                              hipStream_t stream) {
    const float* x   = (const float*)d_in[0];
    const float* att = (const float*)d_in[1];
    float* pT  = (float*)d_ws;      // 152 * 4096 floats = ~2.5 MB
    float* out = (float*)d_out;

    argmax_hist_kernel<<<BB * 64, 512, 0, stream>>>(x, pT);
    apply_kernel<<<152 * 8, 256, 0, stream>>>(x, att, pT, out);
}